// Round 9
// baseline (779.630 us; speedup 1.0000x reference)
//
#include <hip/hip_runtime.h>

// GCN 2-layer forward on MI355X (gfx950).
// R9 (= R8 with macro-paste fix): agg1 reverted to R5 form (128-thr blocks);
//     gemm1 distance-2 A-prefetch, launch_bounds(512,4); fill fused into gemm.

#define NN 100000
#define NE 1600000
#define INC 768
#define HID 256
#define NCLS 8
#define NBLK 391    // ceil(NN/256)
#define GEMMB 782   // gemm blocks
#define FILLB 3125  // NE/512

typedef short bf16x8 __attribute__((ext_vector_type(8)));
typedef float f32x4 __attribute__((ext_vector_type(4)));

__device__ __forceinline__ unsigned short f2bf(float f) {
  unsigned int u = __float_as_uint(f);
  unsigned int r = (u + 0x7FFFu + ((u >> 16) & 1u)) >> 16;  // RNE
  return (unsigned short)r;
}
__device__ __forceinline__ float bf2f(unsigned short h) {
  return __uint_as_float(((unsigned int)h) << 16);
}

// ---------- degree ----------
__global__ __launch_bounds__(256) void k_count(const int* __restrict__ ei, int* __restrict__ cnt) {
  int e = blockIdx.x * 256 + threadIdx.x;
  if (e < NE) atomicAdd(&cnt[ei[NE + e]], 1);  // col = targets
}

// ---------- CSR: 3-phase exclusive scan (scan1 also emits dinv) ----------
__global__ __launch_bounds__(256) void k_scan1(const int* __restrict__ cnt, int* __restrict__ bsum,
                                               float* __restrict__ dinv) {
  __shared__ int s[256];
  int i = blockIdx.x * 256 + threadIdx.x;
  int v = (i < NN) ? cnt[i] : 0;
  if (i < NN) dinv[i] = rsqrtf((float)v + 1.0f);  // +1 self-loop
  s[threadIdx.x] = v;
  __syncthreads();
#pragma unroll
  for (int off = 128; off > 0; off >>= 1) {
    if (threadIdx.x < off) s[threadIdx.x] += s[threadIdx.x + off];
    __syncthreads();
  }
  if (threadIdx.x == 0) bsum[blockIdx.x] = s[0];
}
__global__ __launch_bounds__(512) void k_scan2(const int* __restrict__ bsum, int* __restrict__ boff,
                                               int* __restrict__ rowptr) {
  __shared__ int s[512];
  int tid = threadIdx.x;
  int v = (tid < NBLK) ? bsum[tid] : 0;
  s[tid] = v;
  __syncthreads();
#pragma unroll
  for (int off = 1; off < 512; off <<= 1) {
    int t = (tid >= off) ? s[tid - off] : 0;
    __syncthreads();
    s[tid] += t;
    __syncthreads();
  }
  if (tid < NBLK) boff[tid] = s[tid] - v;
  if (tid == NBLK - 1) rowptr[NN] = s[tid];
}
__global__ __launch_bounds__(256) void k_scan3(const int* __restrict__ cnt, const int* __restrict__ boff,
                                               int* __restrict__ rowptr, int* __restrict__ cursor) {
  __shared__ int s[256];
  int i = blockIdx.x * 256 + threadIdx.x;
  int v = (i < NN) ? cnt[i] : 0;
  s[threadIdx.x] = v;
  __syncthreads();
#pragma unroll
  for (int off = 1; off < 256; off <<= 1) {
    int t = (threadIdx.x >= off) ? s[threadIdx.x - off] : 0;
    __syncthreads();
    s[threadIdx.x] += t;
    __syncthreads();
  }
  if (i < NN) {
    int e = boff[blockIdx.x] + s[threadIdx.x] - v;
    rowptr[i] = e;
    cursor[i] = e;
  }
}

// ---------- W1 transpose+cast ----------
__global__ __launch_bounds__(256) void k_w1t(const float* __restrict__ W1, unsigned short* __restrict__ w1t) {
  int t = blockIdx.x * 256 + threadIdx.x;
  if (t >= INC * HID) return;
  int k = t / HID, n = t % HID;
  w1t[n * INC + k] = f2bf(W1[t]);
}

// ---------- fused GEMM1 + fill ----------
// blocks [0,782): h1 = x @ W1 (128x256 tile, BK=64, dist-2 A prefetch)
// blocks [782, 782+3125): epk fill (scatter via cursor)
__global__ __launch_bounds__(512, 4) void k_gemm_fill(const float* __restrict__ x,
                                                      const unsigned short* __restrict__ w1t,
                                                      unsigned short* __restrict__ h1,
                                                      const int* __restrict__ ei,
                                                      const float* __restrict__ dinv,
                                                      int* __restrict__ cursor,
                                                      int2* __restrict__ epk) {
  __shared__ char smem[49152];
  if (blockIdx.x >= GEMMB) {
    // ---- fill part ----
    int e = (blockIdx.x - GEMMB) * 512 + threadIdx.x;
    if (e < NE) {
      int r = ei[e];         // source
      int c = ei[NE + e];    // target
      float w = dinv[r] * dinv[c];
      int pos = atomicAdd(&cursor[c], 1);
      epk[pos] = make_int2(r, __float_as_int(w));
    }
    return;
  }
  // ---- gemm part ----
  unsigned short* As = (unsigned short*)smem;
  unsigned short* Bs = (unsigned short*)(smem + 16384);
  const int tid = threadIdx.x;
  const int lane = tid & 63;
  const int wid = tid >> 6;
  const int wm = wid >> 2;
  const int wn = wid & 3;
  const long bm = blockIdx.x;

  const int ar0 = tid >> 3, as7 = tid & 7;
  const int ar1 = (tid + 512) >> 3;
  long arow0 = bm * 128 + ar0; if (arow0 > NN - 1) arow0 = NN - 1;
  long arow1 = bm * 128 + ar1; if (arow1 > NN - 1) arow1 = NN - 1;
  const float* gA0 = x + arow0 * INC + as7 * 8;
  const float* gA1 = x + arow1 * INC + as7 * 8;
  const int aoff0 = (ar0 << 7) | ((as7 ^ (ar0 & 7)) << 4);
  const int aoff1 = (ar1 << 7) | ((as7 ^ (ar1 & 7)) << 4);

  f32x4 acc[4][4];
#pragma unroll
  for (int m = 0; m < 4; m++)
#pragma unroll
    for (int n = 0; n < 4; n++) acc[m][n] = (f32x4){0.f, 0.f, 0.f, 0.f};

  // A prefetch sets: Pa..Pd (even tiles), Qa..Qd (odd tiles); B single set rb
  float4 Pa, Pb, Pc, Pd, Qa, Qb, Qc, Qd;
  uint4 rb0, rb1, rb2, rb3;

#define LOAD_ASET(Va, Vb, Vc, Vd, KT)             \
  do {                                            \
    Va = *(const float4*)(gA0 + (KT));            \
    Vb = *(const float4*)(gA0 + (KT) + 4);        \
    Vc = *(const float4*)(gA1 + (KT));            \
    Vd = *(const float4*)(gA1 + (KT) + 4);        \
  } while (0)
#define LOAD_B(KT)                                                                         \
  do {                                                                                     \
    rb0 = *(const uint4*)(w1t + (long)(tid >> 3) * INC + (KT) + (tid & 7) * 8);            \
    rb1 = *(const uint4*)(w1t + (long)((tid + 512) >> 3) * INC + (KT) + (tid & 7) * 8);    \
    rb2 = *(const uint4*)(w1t + (long)((tid + 1024) >> 3) * INC + (KT) + (tid & 7) * 8);   \
    rb3 = *(const uint4*)(w1t + (long)((tid + 1536) >> 3) * INC + (KT) + (tid & 7) * 8);   \
  } while (0)
#define WRITE_ASET(Va, Vb, Vc, Vd)                                                         \
  do {                                                                                     \
    union { unsigned short us[8]; uint4 v; } u;                                            \
    u.us[0] = f2bf(Va.x); u.us[1] = f2bf(Va.y); u.us[2] = f2bf(Va.z);                      \
    u.us[3] = f2bf(Va.w); u.us[4] = f2bf(Vb.x); u.us[5] = f2bf(Vb.y);                      \
    u.us[6] = f2bf(Vb.z); u.us[7] = f2bf(Vb.w);                                            \
    *(uint4*)((char*)As + aoff0) = u.v;                                                    \
    u.us[0] = f2bf(Vc.x); u.us[1] = f2bf(Vc.y); u.us[2] = f2bf(Vc.z);                      \
    u.us[3] = f2bf(Vc.w); u.us[4] = f2bf(Vd.x); u.us[5] = f2bf(Vd.y);                      \
    u.us[6] = f2bf(Vd.z); u.us[7] = f2bf(Vd.w);                                            \
    *(uint4*)((char*)As + aoff1) = u.v;                                                    \
  } while (0)
#define WRITE_B()                                                                          \
  do {                                                                                     \
    int r0 = tid >> 3, s7 = tid & 7;                                                       \
    *(uint4*)((char*)Bs + ((r0 << 7) | ((s7 ^ (r0 & 7)) << 4))) = rb0;                     \
    int r1 = (tid + 512) >> 3;                                                             \
    *(uint4*)((char*)Bs + ((r1 << 7) | ((s7 ^ (r1 & 7)) << 4))) = rb1;                     \
    int r2 = (tid + 1024) >> 3;                                                            \
    *(uint4*)((char*)Bs + ((r2 << 7) | ((s7 ^ (r2 & 7)) << 4))) = rb2;                     \
    int r3 = (tid + 1536) >> 3;                                                            \
    *(uint4*)((char*)Bs + ((r3 << 7) | ((s7 ^ (r3 & 7)) << 4))) = rb3;                     \
  } while (0)
#define MFMA_STEP()                                                                        \
  do {                                                                                     \
    _Pragma("unroll")                                                                      \
    for (int half = 0; half < 2; half++) {                                                 \
      bf16x8 af[4], bff[4];                                                                \
      int j = (half << 2) + (lane >> 4);                                                   \
      _Pragma("unroll")                                                                    \
      for (int m = 0; m < 4; m++) {                                                        \
        int row = wm * 64 + m * 16 + (lane & 15);                                          \
        af[m] = *(const bf16x8*)((const char*)As + ((row << 7) | ((j ^ (row & 7)) << 4))); \
      }                                                                                    \
      _Pragma("unroll")                                                                    \
      for (int n = 0; n < 4; n++) {                                                        \
        int row = wn * 64 + n * 16 + (lane & 15);                                          \
        bff[n] = *(const bf16x8*)((const char*)Bs + ((row << 7) | ((j ^ (row & 7)) << 4)));\
      }                                                                                    \
      _Pragma("unroll")                                                                    \
      for (int m = 0; m < 4; m++)                                                          \
        _Pragma("unroll")                                                                  \
        for (int n = 0; n < 4; n++)                                                        \
          acc[m][n] = __builtin_amdgcn_mfma_f32_16x16x32_bf16(af[m], bff[n], acc[m][n], 0, 0, 0); \
    }                                                                                      \
  } while (0)

  // prologue: A tile0 -> P, B tile0 -> rb, A tile1 -> Q (2 A-tiles in flight)
  LOAD_ASET(Pa, Pb, Pc, Pd, 0);
  LOAD_B(0);
  LOAD_ASET(Qa, Qb, Qc, Qd, 64);

#pragma unroll 1
  for (int u = 0; u < 6; u++) {
    int kt = u * 128;
    // even tile kt (in P)
    WRITE_ASET(Pa, Pb, Pc, Pd);   // waits A@kt, leaves Q (tile kt+64) in flight
    WRITE_B();                    // waits B@kt
    __syncthreads();
    if (kt + 64 < INC) LOAD_B(kt + 64);                      // B issued BEFORE A
    if (kt + 128 < INC) LOAD_ASET(Pa, Pb, Pc, Pd, kt + 128); // A dist-2
    MFMA_STEP();
    __syncthreads();
    // odd tile kt+64 (in Q)
    WRITE_ASET(Qa, Qb, Qc, Qd);
    WRITE_B();
    __syncthreads();
    if (kt + 128 < INC) LOAD_B(kt + 128);
    if (kt + 192 < INC) LOAD_ASET(Qa, Qb, Qc, Qd, kt + 192);
    MFMA_STEP();
    __syncthreads();
  }
#undef LOAD_ASET
#undef LOAD_B
#undef WRITE_ASET
#undef WRITE_B
#undef MFMA_STEP

  // epilogue: stage 64-row half-tiles in LDS, copy out full rows
  unsigned short* Os = (unsigned short*)smem;  // [64][264]
#pragma unroll
  for (int chunk = 0; chunk < 2; chunk++) {
    if (wm == chunk) {
#pragma unroll
      for (int m = 0; m < 4; m++)
#pragma unroll
        for (int n = 0; n < 4; n++) {
          int lrow = m * 16 + ((lane >> 4) << 2);
          int lcol = wn * 64 + n * 16 + (lane & 15);
#pragma unroll
          for (int r = 0; r < 4; r++)
            Os[(lrow + r) * 264 + lcol] = f2bf(acc[m][n][r]);
        }
    }
    __syncthreads();
    {
      int r = tid >> 3, s = tid & 7;
      long grow = bm * 128 + chunk * 64 + r;
      if (grow < NN) {
        unsigned short* dst = h1 + grow * HID;
#pragma unroll
        for (int i = 0; i < 4; i++) {
          int seg = s + i * 8;
          *(uint4*)(dst + seg * 8) = *(const uint4*)((const char*)Os + (long)r * 528 + seg * 16);
        }
      }
    }
    __syncthreads();
  }
}

// ---------- agg1 fused with relu+b1+W2 (R5 form: wave/node, ushort4, unroll x8) ----------
__global__ __launch_bounds__(128) void k_agg1(const unsigned short* __restrict__ h1,
                                              const float* __restrict__ dinv,
                                              const int* __restrict__ rowptr,
                                              const int2* __restrict__ epk,
                                              const float* __restrict__ b1,
                                              const float* __restrict__ W2,
                                              float* __restrict__ h2) {
  int w = (int)((blockIdx.x * 128 + threadIdx.x) >> 6);
  int lane = threadIdx.x & 63;
  if (w >= NN) return;
  float di = dinv[w];
  int c4 = lane << 2;
  const unsigned short* hb = h1 + c4;
  ushort4 hv = *(const ushort4*)(hb + (long)w * HID);
  float self = di * di;
  float a0 = self * bf2f(hv.x), a1 = self * bf2f(hv.y);
  float a2 = self * bf2f(hv.z), a3 = self * bf2f(hv.w);
  int e = rowptr[w], e1 = rowptr[w + 1];
  if ((e & 1) && e < e1) {
    int2 q = epk[e];
    float ws = __int_as_float(q.y);
    ushort4 g = *(const ushort4*)(hb + (long)q.x * HID);
    a0 += ws * bf2f(g.x); a1 += ws * bf2f(g.y);
    a2 += ws * bf2f(g.z); a3 += ws * bf2f(g.w);
    e++;
  }
  for (; e + 8 <= e1; e += 8) {
    uint4 p0 = *(const uint4*)(epk + e);
    uint4 p1 = *(const uint4*)(epk + e + 2);
    uint4 p2 = *(const uint4*)(epk + e + 4);
    uint4 p3 = *(const uint4*)(epk + e + 6);
    ushort4 g0 = *(const ushort4*)(hb + (long)(int)p0.x * HID);
    ushort4 g1 = *(const ushort4*)(hb + (long)(int)p0.z * HID);
    ushort4 g2 = *(const ushort4*)(hb + (long)(int)p1.x * HID);
    ushort4 g3 = *(const ushort4*)(hb + (long)(int)p1.z * HID);
    ushort4 g4 = *(const ushort4*)(hb + (long)(int)p2.x * HID);
    ushort4 g5 = *(const ushort4*)(hb + (long)(int)p2.z * HID);
    ushort4 g6 = *(const ushort4*)(hb + (long)(int)p3.x * HID);
    ushort4 g7 = *(const ushort4*)(hb + (long)(int)p3.z * HID);
    float w0 = __uint_as_float(p0.y), w1 = __uint_as_float(p0.w);
    float w2 = __uint_as_float(p1.y), w3 = __uint_as_float(p1.w);
    float w4 = __uint_as_float(p2.y), w5 = __uint_as_float(p2.w);
    float w6 = __uint_as_float(p3.y), w7 = __uint_as_float(p3.w);
    a0 += w0 * bf2f(g0.x) + w1 * bf2f(g1.x) + w2 * bf2f(g2.x) + w3 * bf2f(g3.x) +
          w4 * bf2f(g4.x) + w5 * bf2f(g5.x) + w6 * bf2f(g6.x) + w7 * bf2f(g7.x);
    a1 += w0 * bf2f(g0.y) + w1 * bf2f(g1.y) + w2 * bf2f(g2.y) + w3 * bf2f(g3.y) +
          w4 * bf2f(g4.y) + w5 * bf2f(g5.y) + w6 * bf2f(g6.y) + w7 * bf2f(g7.y);
    a2 += w0 * bf2f(g0.z) + w1 * bf2f(g1.z) + w2 * bf2f(g2.z) + w3 * bf2f(g3.z) +
          w4 * bf2f(g4.z) + w5 * bf2f(g5.z) + w6 * bf2f(g6.z) + w7 * bf2f(g7.z);
    a3 += w0 * bf2f(g0.w) + w1 * bf2f(g1.w) + w2 * bf2f(g2.w) + w3 * bf2f(g3.w) +
          w4 * bf2f(g4.w) + w5 * bf2f(g5.w) + w6 * bf2f(g6.w) + w7 * bf2f(g7.w);
  }
  for (; e + 2 <= e1; e += 2) {
    uint4 p = *(const uint4*)(epk + e);
    ushort4 g0 = *(const ushort4*)(hb + (long)(int)p.x * HID);
    ushort4 g1 = *(const ushort4*)(hb + (long)(int)p.z * HID);
    float w0 = __uint_as_float(p.y), w1 = __uint_as_float(p.w);
    a0 += w0 * bf2f(g0.x) + w1 * bf2f(g1.x);
    a1 += w0 * bf2f(g0.y) + w1 * bf2f(g1.y);
    a2 += w0 * bf2f(g0.z) + w1 * bf2f(g1.z);
    a3 += w0 * bf2f(g0.w) + w1 * bf2f(g1.w);
  }
  if (e < e1) {
    int2 q = epk[e];
    float ws = __int_as_float(q.y);
    ushort4 g = *(const ushort4*)(hb + (long)q.x * HID);
    a0 += ws * bf2f(g.x); a1 += ws * bf2f(g.y);
    a2 += ws * bf2f(g.z); a3 += ws * bf2f(g.w);
  }
  float4 bv = *(const float4*)(b1 + c4);
  float v0 = a0 + bv.x; v0 = v0 > 0.f ? v0 : 0.f;
  float v1 = a1 + bv.y; v1 = v1 > 0.f ? v1 : 0.f;
  float v2 = a2 + bv.z; v2 = v2 > 0.f ? v2 : 0.f;
  float v3 = a3 + bv.w; v3 = v3 > 0.f ? v3 : 0.f;
  const float4* wp = (const float4*)(W2 + ((long)c4 << 3));
  float4 r0a = wp[0], r0b = wp[1], r1a = wp[2], r1b = wp[3];
  float4 r2a = wp[4], r2b = wp[5], r3a = wp[6], r3b = wp[7];
  float p[8];
  p[0] = v0 * r0a.x + v1 * r1a.x + v2 * r2a.x + v3 * r3a.x;
  p[1] = v0 * r0a.y + v1 * r1a.y + v2 * r2a.y + v3 * r3a.y;
  p[2] = v0 * r0a.z + v1 * r1a.z + v2 * r2a.z + v3 * r3a.z;
  p[3] = v0 * r0a.w + v1 * r1a.w + v2 * r2a.w + v3 * r3a.w;
  p[4] = v0 * r0b.x + v1 * r1b.x + v2 * r2b.x + v3 * r3b.x;
  p[5] = v0 * r0b.y + v1 * r1b.y + v2 * r2b.y + v3 * r3b.y;
  p[6] = v0 * r0b.z + v1 * r1b.z + v2 * r2b.z + v3 * r3b.z;
  p[7] = v0 * r0b.w + v1 * r1b.w + v2 * r2b.w + v3 * r3b.w;
#pragma unroll
  for (int c = 0; c < 8; c++)
#pragma unroll
    for (int off = 1; off < 64; off <<= 1) p[c] += __shfl_xor(p[c], off, 64);
  if (lane < 8) {
    float o = p[0];
    o = (lane == 1) ? p[1] : o;
    o = (lane == 2) ? p[2] : o;
    o = (lane == 3) ? p[3] : o;
    o = (lane == 4) ? p[4] : o;
    o = (lane == 5) ? p[5] : o;
    o = (lane == 6) ? p[6] : o;
    o = (lane == 7) ? p[7] : o;
    h2[(long)w * NCLS + lane] = o;
  }
}

// ---------- agg2 + bias -> out (unroll x8) ----------
__global__ __launch_bounds__(256) void k_agg2(const float* __restrict__ h2,
                                              const float* __restrict__ dinv,
                                              const int* __restrict__ rowptr,
                                              const int2* __restrict__ epk,
                                              const float* __restrict__ b2,
                                              float* __restrict__ out) {
  long t = (long)blockIdx.x * 256 + threadIdx.x;
  long i = t >> 3;
  int c = (int)(t & 7);
  if (i >= NN) return;
  float di = dinv[i];
  float s = di * di * h2[i * NCLS + c];
  int e = rowptr[i], e1 = rowptr[i + 1];
  for (; e + 8 <= e1; e += 8) {
    int2 q0 = epk[e],     q1 = epk[e + 1], q2 = epk[e + 2], q3 = epk[e + 3];
    int2 q4 = epk[e + 4], q5 = epk[e + 5], q6 = epk[e + 6], q7 = epk[e + 7];
    float g0 = h2[(long)q0.x * NCLS + c], g1 = h2[(long)q1.x * NCLS + c];
    float g2 = h2[(long)q2.x * NCLS + c], g3 = h2[(long)q3.x * NCLS + c];
    float g4 = h2[(long)q4.x * NCLS + c], g5 = h2[(long)q5.x * NCLS + c];
    float g6 = h2[(long)q6.x * NCLS + c], g7 = h2[(long)q7.x * NCLS + c];
    s += __int_as_float(q0.y) * g0 + __int_as_float(q1.y) * g1 +
         __int_as_float(q2.y) * g2 + __int_as_float(q3.y) * g3 +
         __int_as_float(q4.y) * g4 + __int_as_float(q5.y) * g5 +
         __int_as_float(q6.y) * g6 + __int_as_float(q7.y) * g7;
  }
  for (; e < e1; e++) {
    int2 q = epk[e];
    s += __int_as_float(q.y) * h2[(long)q.x * NCLS + c];
  }
  out[i * NCLS + c] = s + b2[c];
}

extern "C" void kernel_launch(void* const* d_in, const int* in_sizes, int n_in,
                              void* d_out, int out_size, void* d_ws, size_t ws_size,
                              hipStream_t stream) {
  (void)in_sizes; (void)n_in; (void)out_size; (void)ws_size;
  const float* x  = (const float*)d_in[0];
  const int*   ei = (const int*)d_in[1];
  const float* W1 = (const float*)d_in[2];
  const float* b1 = (const float*)d_in[3];
  const float* W2 = (const float*)d_in[4];
  const float* b2 = (const float*)d_in[5];
  float* out = (float*)d_out;
  char* ws = (char*)d_ws;

  unsigned short* h1   = (unsigned short*)(ws + 0L);          // 51,200,000
  float* h2            = (float*)(ws + 51200000L);            // 3,200,000
  float* dinv          = (float*)(ws + 54400000L);            // 400,000
  int*   cnt           = (int*)(ws + 54800000L);              // 400,000
  int*   rowptr        = (int*)(ws + 55200000L);              // 400,004 (+pad)
  int*   cursor        = (int*)(ws + 55600128L);              // 400,000
  int2*  epk           = (int2*)(ws + 56000128L);             // 12,800,000
  unsigned short* w1t  = (unsigned short*)(ws + 68800128L);   // 393,216
  int*   bsum          = (int*)(ws + 69195008L);              // 1,564
  int*   boff          = (int*)(ws + 69196608L);              // 1,564

  hipMemsetAsync(cnt, 0, NN * sizeof(int), stream);
  k_count<<<(NE + 255) / 256, 256, 0, stream>>>(ei, cnt);
  k_scan1<<<NBLK, 256, 0, stream>>>(cnt, bsum, dinv);
  k_scan2<<<1, 512, 0, stream>>>(bsum, boff, rowptr);
  k_scan3<<<NBLK, 256, 0, stream>>>(cnt, boff, rowptr, cursor);
  k_w1t<<<(INC * HID + 255) / 256, 256, 0, stream>>>(W1, w1t);
  k_gemm_fill<<<GEMMB + FILLB, 512, 0, stream>>>(x, w1t, h1, ei, dinv, cursor, epk);
  k_agg1<<<(NN * 64 + 127) / 128, 128, 0, stream>>>(h1, dinv, rowptr, epk, b1, W2, h2);
  k_agg2<<<(NN * NCLS + 255) / 256, 256, 0, stream>>>(h2, dinv, rowptr, epk, b2, out);
}

// Round 10
// 712.156 us; speedup vs baseline: 1.0947x; 1.0947x over previous
//
#include <hip/hip_runtime.h>

// GCN 2-layer forward on MI355X (gfx950).
// R10: agg1 -> XCD-L2 slab pinning. h1 stored slab-major h1t[16][NN][16ch]
//      (3.2MB/slab < 4MB L2); 16 slab passes, blockIdx%8 pins slab->XCD,
//      2 epochs of 8 slabs sequence via grid > resident capacity.
//      Self-loop folded into epk (scans use cnt+1, k_selffill). W2 unfused ->
//      agg1b bf16 + k_l2. GEMM = R5 form with slab-major epilogue. Fill separate
//      (R9 lesson: scatter must own L2).

#define NN 100000
#define NE 1600000
#define NEPK 1700000   // NE + NN self-loops
#define INC 768
#define HID 256
#define NCLS 8
#define NBLK 391       // ceil(NN/256)
#define SLABN 1600000L // NN*16 shorts per slab

typedef short bf16x8 __attribute__((ext_vector_type(8)));
typedef float f32x4 __attribute__((ext_vector_type(4)));

__device__ __forceinline__ unsigned short f2bf(float f) {
  unsigned int u = __float_as_uint(f);
  unsigned int r = (u + 0x7FFFu + ((u >> 16) & 1u)) >> 16;  // RNE
  return (unsigned short)r;
}
__device__ __forceinline__ float bf2f(unsigned short h) {
  return __uint_as_float(((unsigned int)h) << 16);
}

// ---------- degree ----------
__global__ __launch_bounds__(256) void k_count(const int* __restrict__ ei, int* __restrict__ cnt) {
  int e = blockIdx.x * 256 + threadIdx.x;
  if (e < NE) atomicAdd(&cnt[ei[NE + e]], 1);  // col = targets
}

// ---------- CSR over E+N entries (deg = cnt+1 incl self-loop) ----------
__global__ __launch_bounds__(256) void k_scan1(const int* __restrict__ cnt, int* __restrict__ bsum,
                                               float* __restrict__ dinv) {
  __shared__ int s[256];
  int i = blockIdx.x * 256 + threadIdx.x;
  int v = (i < NN) ? (cnt[i] + 1) : 0;
  if (i < NN) dinv[i] = rsqrtf((float)v);
  s[threadIdx.x] = v;
  __syncthreads();
#pragma unroll
  for (int off = 128; off > 0; off >>= 1) {
    if (threadIdx.x < off) s[threadIdx.x] += s[threadIdx.x + off];
    __syncthreads();
  }
  if (threadIdx.x == 0) bsum[blockIdx.x] = s[0];
}
__global__ __launch_bounds__(512) void k_scan2(const int* __restrict__ bsum, int* __restrict__ boff,
                                               int* __restrict__ rowptr) {
  __shared__ int s[512];
  int tid = threadIdx.x;
  int v = (tid < NBLK) ? bsum[tid] : 0;
  s[tid] = v;
  __syncthreads();
#pragma unroll
  for (int off = 1; off < 512; off <<= 1) {
    int t = (tid >= off) ? s[tid - off] : 0;
    __syncthreads();
    s[tid] += t;
    __syncthreads();
  }
  if (tid < NBLK) boff[tid] = s[tid] - v;
  if (tid == NBLK - 1) rowptr[NN] = s[tid];
}
__global__ __launch_bounds__(256) void k_scan3(const int* __restrict__ cnt, const int* __restrict__ boff,
                                               int* __restrict__ rowptr, int* __restrict__ cursor) {
  __shared__ int s[256];
  int i = blockIdx.x * 256 + threadIdx.x;
  int v = (i < NN) ? (cnt[i] + 1) : 0;
  s[threadIdx.x] = v;
  __syncthreads();
#pragma unroll
  for (int off = 1; off < 256; off <<= 1) {
    int t = (threadIdx.x >= off) ? s[threadIdx.x - off] : 0;
    __syncthreads();
    s[threadIdx.x] += t;
    __syncthreads();
  }
  if (i < NN) {
    int e = boff[blockIdx.x] + s[threadIdx.x] - v;
    rowptr[i] = e;
    cursor[i] = e;
  }
}
__global__ __launch_bounds__(256) void k_fill(const int* __restrict__ ei, const float* __restrict__ dinv,
                                              int* __restrict__ cursor, int2* __restrict__ epk) {
  int e = blockIdx.x * 256 + threadIdx.x;
  if (e >= NE) return;
  int r = ei[e];         // source
  int c = ei[NE + e];    // target
  float w = dinv[r] * dinv[c];
  int pos = atomicAdd(&cursor[c], 1);
  epk[pos] = make_int2(r, __float_as_int(w));
}
__global__ __launch_bounds__(256) void k_selffill(const float* __restrict__ dinv,
                                                  int* __restrict__ cursor, int2* __restrict__ epk) {
  int i = blockIdx.x * 256 + threadIdx.x;
  if (i >= NN) return;
  float d = dinv[i];
  int pos = atomicAdd(&cursor[i], 1);
  epk[pos] = make_int2(i, __float_as_int(d * d));
}

// ---------- W1 transpose+cast ----------
__global__ __launch_bounds__(256) void k_w1t(const float* __restrict__ W1, unsigned short* __restrict__ w1t) {
  int t = blockIdx.x * 256 + threadIdx.x;
  if (t >= INC * HID) return;
  int k = t / HID, n = t % HID;
  w1t[n * INC + k] = f2bf(W1[t]);
}

// ---------- GEMM1 (R5 pipelined) with slab-major epilogue ----------
__global__ __launch_bounds__(512) void k_gemm1(const float* __restrict__ x,
                                               const unsigned short* __restrict__ w1t,
                                               unsigned short* __restrict__ h1t) {
  __shared__ char smem[49152];
  unsigned short* As = (unsigned short*)smem;
  unsigned short* Bs = (unsigned short*)(smem + 16384);
  const int tid = threadIdx.x;
  const int lane = tid & 63;
  const int wid = tid >> 6;
  const int wm = wid >> 2;
  const int wn = wid & 3;
  const long bm = blockIdx.x;

  const int ar0 = tid >> 3, as7 = tid & 7;
  const int ar1 = (tid + 512) >> 3;
  long arow0 = bm * 128 + ar0; if (arow0 > NN - 1) arow0 = NN - 1;
  long arow1 = bm * 128 + ar1; if (arow1 > NN - 1) arow1 = NN - 1;
  const float* gA0 = x + arow0 * INC + as7 * 8;
  const float* gA1 = x + arow1 * INC + as7 * 8;
  const int aoff0 = (ar0 << 7) | ((as7 ^ (ar0 & 7)) << 4);
  const int aoff1 = (ar1 << 7) | ((as7 ^ (ar1 & 7)) << 4);

  f32x4 acc[4][4];
#pragma unroll
  for (int m = 0; m < 4; m++)
#pragma unroll
    for (int n = 0; n < 4; n++) acc[m][n] = (f32x4){0.f, 0.f, 0.f, 0.f};

  float4 fa00, fa01, fa10, fa11;
  uint4 rb0, rb1, rb2, rb3;

#define LOAD_AB(KT)                                                        \
  do {                                                                     \
    fa00 = *(const float4*)(gA0 + (KT));                                   \
    fa01 = *(const float4*)(gA0 + (KT) + 4);                               \
    fa10 = *(const float4*)(gA1 + (KT));                                   \
    fa11 = *(const float4*)(gA1 + (KT) + 4);                               \
    rb0 = *(const uint4*)(w1t + (long)(tid >> 3) * INC + (KT) + (tid & 7) * 8);            \
    rb1 = *(const uint4*)(w1t + (long)((tid + 512) >> 3) * INC + (KT) + (tid & 7) * 8);    \
    rb2 = *(const uint4*)(w1t + (long)((tid + 1024) >> 3) * INC + (KT) + (tid & 7) * 8);   \
    rb3 = *(const uint4*)(w1t + (long)((tid + 1536) >> 3) * INC + (KT) + (tid & 7) * 8);   \
  } while (0)

  LOAD_AB(0);

  for (int kt = 0; kt < INC; kt += 64) {
    {
      union { unsigned short us[8]; uint4 v; } u;
      u.us[0] = f2bf(fa00.x); u.us[1] = f2bf(fa00.y); u.us[2] = f2bf(fa00.z); u.us[3] = f2bf(fa00.w);
      u.us[4] = f2bf(fa01.x); u.us[5] = f2bf(fa01.y); u.us[6] = f2bf(fa01.z); u.us[7] = f2bf(fa01.w);
      *(uint4*)((char*)As + aoff0) = u.v;
      u.us[0] = f2bf(fa10.x); u.us[1] = f2bf(fa10.y); u.us[2] = f2bf(fa10.z); u.us[3] = f2bf(fa10.w);
      u.us[4] = f2bf(fa11.x); u.us[5] = f2bf(fa11.y); u.us[6] = f2bf(fa11.z); u.us[7] = f2bf(fa11.w);
      *(uint4*)((char*)As + aoff1) = u.v;
    }
    {
      int r0 = tid >> 3, s7 = tid & 7;
      *(uint4*)((char*)Bs + ((r0 << 7) | ((s7 ^ (r0 & 7)) << 4))) = rb0;
      int r1 = (tid + 512) >> 3;
      *(uint4*)((char*)Bs + ((r1 << 7) | ((s7 ^ (r1 & 7)) << 4))) = rb1;
      int r2 = (tid + 1024) >> 3;
      *(uint4*)((char*)Bs + ((r2 << 7) | ((s7 ^ (r2 & 7)) << 4))) = rb2;
      int r3 = (tid + 1536) >> 3;
      *(uint4*)((char*)Bs + ((r3 << 7) | ((s7 ^ (r3 & 7)) << 4))) = rb3;
    }
    __syncthreads();
    if (kt + 64 < INC) LOAD_AB(kt + 64);
#pragma unroll
    for (int half = 0; half < 2; half++) {
      bf16x8 af[4], bff[4];
      int j = (half << 2) + (lane >> 4);
#pragma unroll
      for (int m = 0; m < 4; m++) {
        int row = wm * 64 + m * 16 + (lane & 15);
        int off = (row << 7) | ((j ^ (row & 7)) << 4);
        af[m] = *(const bf16x8*)((const char*)As + off);
      }
#pragma unroll
      for (int n = 0; n < 4; n++) {
        int row = wn * 64 + n * 16 + (lane & 15);
        int off = (row << 7) | ((j ^ (row & 7)) << 4);
        bff[n] = *(const bf16x8*)((const char*)Bs + off);
      }
#pragma unroll
      for (int m = 0; m < 4; m++)
#pragma unroll
        for (int n = 0; n < 4; n++)
          acc[m][n] = __builtin_amdgcn_mfma_f32_16x16x32_bf16(af[m], bff[n], acc[m][n], 0, 0, 0);
    }
    __syncthreads();
  }
#undef LOAD_AB

  // epilogue: stage 64-row half-tiles in LDS, write out slab-major
  unsigned short* Os = (unsigned short*)smem;  // [64][264]
#pragma unroll
  for (int chunk = 0; chunk < 2; chunk++) {
    if (wm == chunk) {
#pragma unroll
      for (int m = 0; m < 4; m++)
#pragma unroll
        for (int n = 0; n < 4; n++) {
          int lrow = m * 16 + ((lane >> 4) << 2);
          int lcol = wn * 64 + n * 16 + (lane & 15);
#pragma unroll
          for (int r = 0; r < 4; r++)
            Os[(lrow + r) * 264 + lcol] = f2bf(acc[m][n][r]);
        }
    }
    __syncthreads();
#pragma unroll
    for (int i = 0; i < 4; i++) {
      int idx = i * 512 + tid;           // 0..2047 = 16 slabs x 64 rows x 2 halves
      int slab = idx >> 7;
      int row = (idx >> 1) & 63;
      int half = idx & 1;
      long grow = bm * 128 + chunk * 64 + row;
      if (grow < NN)
        *(uint4*)(h1t + (long)slab * SLABN + grow * 16 + half * 8) =
            *(const uint4*)((const char*)Os + (long)row * 528 + slab * 32 + half * 16);
    }
    __syncthreads();
  }
}

// ---------- agg1 slab pass: agg1b[node][256] (bf16) = sum_e w * h1t[slab][src] ----------
// grid 4096 = 2 epochs x 8 xcd-slabs x 256 node-blocks. slab -> XCD via blockIdx%8.
__global__ __launch_bounds__(256) void k_agg1s(const unsigned short* __restrict__ h1t,
                                               const int* __restrict__ rowptr,
                                               const int2* __restrict__ epk,
                                               unsigned short* __restrict__ agg1b) {
  int b = blockIdx.x;
  int slab = (b & 7) + ((b >> 11) << 3);  // epoch*8 + xcd
  int j = (b >> 3) & 255;
  int widx = threadIdx.x >> 6;
  int lane = threadIdx.x & 63;
  int slot = lane >> 3, cp = lane & 7;
  const unsigned short* hs = h1t + (long)slab * SLABN + cp * 2;
  int wv = j * 4 + widx;  // 0..1023
  for (int node = wv; node < NN; node += 1024) {
    int e0 = rowptr[node], e1 = rowptr[node + 1];
    float a0 = 0.f, a1 = 0.f;
    for (int e = e0 + slot; e < e1; e += 8) {
      int2 q = epk[e];
      float w = __int_as_float(q.y);
      ushort2 g = *(const ushort2*)(hs + (long)q.x * 16);
      a0 += w * bf2f(g.x);
      a1 += w * bf2f(g.y);
    }
#pragma unroll
    for (int off = 8; off < 64; off <<= 1) {
      a0 += __shfl_xor(a0, off, 64);
      a1 += __shfl_xor(a1, off, 64);
    }
    if (slot == 0) {
      ushort2 o;
      o.x = f2bf(a0);
      o.y = f2bf(a1);
      *(ushort2*)(agg1b + (long)node * HID + slab * 16 + cp * 2) = o;
    }
  }
}

// ---------- layer2 transform: h2 = relu(agg1b + b1) @ W2 ----------
__global__ __launch_bounds__(256) void k_l2(const unsigned short* __restrict__ agg1b,
                                            const float* __restrict__ b1,
                                            const float* __restrict__ W2,
                                            float* __restrict__ h2) {
  __shared__ float w2s[HID * NCLS];
  __shared__ float b1s[HID];
  int tid = threadIdx.x;
  for (int i = tid; i < HID * NCLS; i += 256) w2s[i] = W2[i];
  b1s[tid] = b1[tid];
  __syncthreads();
  long t = (long)blockIdx.x * 256 + tid;
  long i = t >> 3;
  int c = (int)(t & 7);
  if (i >= NN) return;
  const ushort4* ap = (const ushort4*)(agg1b + i * HID);
  float s = 0.f;
#pragma unroll 8
  for (int k4 = 0; k4 < HID / 4; k4++) {
    ushort4 a = ap[k4];
    int k = k4 * 4;
    float v0 = bf2f(a.x) + b1s[k + 0]; v0 = v0 > 0.f ? v0 : 0.f;
    float v1 = bf2f(a.y) + b1s[k + 1]; v1 = v1 > 0.f ? v1 : 0.f;
    float v2 = bf2f(a.z) + b1s[k + 2]; v2 = v2 > 0.f ? v2 : 0.f;
    float v3 = bf2f(a.w) + b1s[k + 3]; v3 = v3 > 0.f ? v3 : 0.f;
    s += v0 * w2s[(k + 0) * NCLS + c] + v1 * w2s[(k + 1) * NCLS + c] +
         v2 * w2s[(k + 2) * NCLS + c] + v3 * w2s[(k + 3) * NCLS + c];
  }
  h2[i * NCLS + c] = s;
}

// ---------- agg2 + bias -> out (self included in epk) ----------
__global__ __launch_bounds__(256) void k_agg2(const float* __restrict__ h2,
                                              const int* __restrict__ rowptr,
                                              const int2* __restrict__ epk,
                                              const float* __restrict__ b2,
                                              float* __restrict__ out) {
  long t = (long)blockIdx.x * 256 + threadIdx.x;
  long i = t >> 3;
  int c = (int)(t & 7);
  if (i >= NN) return;
  float s = 0.f;
  int e = rowptr[i], e1 = rowptr[i + 1];
  for (; e + 8 <= e1; e += 8) {
    int2 q0 = epk[e],     q1 = epk[e + 1], q2 = epk[e + 2], q3 = epk[e + 3];
    int2 q4 = epk[e + 4], q5 = epk[e + 5], q6 = epk[e + 6], q7 = epk[e + 7];
    float g0 = h2[(long)q0.x * NCLS + c], g1 = h2[(long)q1.x * NCLS + c];
    float g2 = h2[(long)q2.x * NCLS + c], g3 = h2[(long)q3.x * NCLS + c];
    float g4 = h2[(long)q4.x * NCLS + c], g5 = h2[(long)q5.x * NCLS + c];
    float g6 = h2[(long)q6.x * NCLS + c], g7 = h2[(long)q7.x * NCLS + c];
    s += __int_as_float(q0.y) * g0 + __int_as_float(q1.y) * g1 +
         __int_as_float(q2.y) * g2 + __int_as_float(q3.y) * g3 +
         __int_as_float(q4.y) * g4 + __int_as_float(q5.y) * g5 +
         __int_as_float(q6.y) * g6 + __int_as_float(q7.y) * g7;
  }
  for (; e < e1; e++) {
    int2 q = epk[e];
    s += __int_as_float(q.y) * h2[(long)q.x * NCLS + c];
  }
  out[i * NCLS + c] = s + b2[c];
}

extern "C" void kernel_launch(void* const* d_in, const int* in_sizes, int n_in,
                              void* d_out, int out_size, void* d_ws, size_t ws_size,
                              hipStream_t stream) {
  (void)in_sizes; (void)n_in; (void)out_size; (void)ws_size;
  const float* x  = (const float*)d_in[0];
  const int*   ei = (const int*)d_in[1];
  const float* W1 = (const float*)d_in[2];
  const float* b1 = (const float*)d_in[3];
  const float* W2 = (const float*)d_in[4];
  const float* b2 = (const float*)d_in[5];
  float* out = (float*)d_out;
  char* ws = (char*)d_ws;

  unsigned short* h1t   = (unsigned short*)(ws + 0L);           // 51,200,000
  unsigned short* agg1b = (unsigned short*)(ws + 51200000L);    // 51,200,000
  float* h2             = (float*)(ws + 102400000L);            // 3,200,000
  float* dinv           = (float*)(ws + 105600000L);            // 400,000
  int*   cnt            = (int*)(ws + 106000000L);              // 400,000
  int*   rowptr         = (int*)(ws + 106400000L);              // 400,004 (+pad)
  int*   cursor         = (int*)(ws + 106800128L);              // 400,000
  int2*  epk            = (int2*)(ws + 107200128L);             // 13,600,000
  unsigned short* w1t   = (unsigned short*)(ws + 120800128L);   // 393,216
  int*   bsum           = (int*)(ws + 121193344L);              // 1,564
  int*   boff           = (int*)(ws + 121194944L);              // 1,564

  hipMemsetAsync(cnt, 0, NN * sizeof(int), stream);
  k_count<<<(NE + 255) / 256, 256, 0, stream>>>(ei, cnt);
  k_scan1<<<NBLK, 256, 0, stream>>>(cnt, bsum, dinv);
  k_scan2<<<1, 512, 0, stream>>>(bsum, boff, rowptr);
  k_scan3<<<NBLK, 256, 0, stream>>>(cnt, boff, rowptr, cursor);
  k_fill<<<(NE + 255) / 256, 256, 0, stream>>>(ei, dinv, cursor, epk);
  k_selffill<<<(NN + 255) / 256, 256, 0, stream>>>(dinv, cursor, epk);
  k_w1t<<<(INC * HID + 255) / 256, 256, 0, stream>>>(W1, w1t);
  k_gemm1<<<782, 512, 0, stream>>>(x, w1t, h1t);
  k_agg1s<<<4096, 256, 0, stream>>>(h1t, rowptr, epk, agg1b);
  k_l2<<<(NN * NCLS + 255) / 256, 256, 0, stream>>>(agg1b, b1, W2, h2);
  k_agg2<<<(NN * NCLS + 255) / 256, 256, 0, stream>>>(h2, rowptr, epk, b2, out);
}

// Round 11
// 455.431 us; speedup vs baseline: 1.7118x; 1.5637x over previous
//
#include <hip/hip_runtime.h>
#include <hip/hip_bf16.h>

// GCN 2-layer forward on MI355X (gfx950).
// R11: revert to R5 base (best: 458us). Deltas: (1) gemm1 dist-2 A-prefetch
//      (clean, unfused — R9's was polluted by fill blocks); (2) native
//      __float2bfloat16 casts (single-instr convert vs 4-op bit RNE).
//      agg1 = R5 form exactly (186us; 5 restructures all regressed).

#define NN 100000
#define NE 1600000
#define INC 768
#define HID 256
#define NCLS 8
#define NBLK 391  // ceil(NN/256)

typedef short bf16x8 __attribute__((ext_vector_type(8)));
typedef float f32x4 __attribute__((ext_vector_type(4)));

__device__ __forceinline__ unsigned short f2bf(float f) {
  __hip_bfloat16 h = __float2bfloat16(f);  // RNE, compiler-native convert
  return *reinterpret_cast<unsigned short*>(&h);
}
__device__ __forceinline__ float bf2f(unsigned short h) {
  return __uint_as_float(((unsigned int)h) << 16);
}

// ---------- degree ----------
__global__ __launch_bounds__(256) void k_count(const int* __restrict__ ei, int* __restrict__ cnt) {
  int e = blockIdx.x * 256 + threadIdx.x;
  if (e < NE) atomicAdd(&cnt[ei[NE + e]], 1);  // col = targets
}

// ---------- CSR: 3-phase exclusive scan (scan1 also emits dinv) ----------
__global__ __launch_bounds__(256) void k_scan1(const int* __restrict__ cnt, int* __restrict__ bsum,
                                               float* __restrict__ dinv) {
  __shared__ int s[256];
  int i = blockIdx.x * 256 + threadIdx.x;
  int v = (i < NN) ? cnt[i] : 0;
  if (i < NN) dinv[i] = rsqrtf((float)v + 1.0f);  // +1 self-loop
  s[threadIdx.x] = v;
  __syncthreads();
#pragma unroll
  for (int off = 128; off > 0; off >>= 1) {
    if (threadIdx.x < off) s[threadIdx.x] += s[threadIdx.x + off];
    __syncthreads();
  }
  if (threadIdx.x == 0) bsum[blockIdx.x] = s[0];
}
__global__ __launch_bounds__(512) void k_scan2(const int* __restrict__ bsum, int* __restrict__ boff,
                                               int* __restrict__ rowptr) {
  __shared__ int s[512];
  int tid = threadIdx.x;
  int v = (tid < NBLK) ? bsum[tid] : 0;
  s[tid] = v;
  __syncthreads();
#pragma unroll
  for (int off = 1; off < 512; off <<= 1) {
    int t = (tid >= off) ? s[tid - off] : 0;
    __syncthreads();
    s[tid] += t;
    __syncthreads();
  }
  if (tid < NBLK) boff[tid] = s[tid] - v;
  if (tid == NBLK - 1) rowptr[NN] = s[tid];
}
__global__ __launch_bounds__(256) void k_scan3(const int* __restrict__ cnt, const int* __restrict__ boff,
                                               int* __restrict__ rowptr, int* __restrict__ cursor) {
  __shared__ int s[256];
  int i = blockIdx.x * 256 + threadIdx.x;
  int v = (i < NN) ? cnt[i] : 0;
  s[threadIdx.x] = v;
  __syncthreads();
#pragma unroll
  for (int off = 1; off < 256; off <<= 1) {
    int t = (threadIdx.x >= off) ? s[threadIdx.x - off] : 0;
    __syncthreads();
    s[threadIdx.x] += t;
    __syncthreads();
  }
  if (i < NN) {
    int e = boff[blockIdx.x] + s[threadIdx.x] - v;
    rowptr[i] = e;
    cursor[i] = e;
  }
}
// fill: per-edge packed (src, dinv[src]*dinv[col])
__global__ __launch_bounds__(256) void k_fill(const int* __restrict__ ei, const float* __restrict__ dinv,
                                              int* __restrict__ cursor, int2* __restrict__ epk) {
  int e = blockIdx.x * 256 + threadIdx.x;
  if (e >= NE) return;
  int r = ei[e];         // source
  int c = ei[NE + e];    // target
  float w = dinv[r] * dinv[c];
  int pos = atomicAdd(&cursor[c], 1);
  epk[pos] = make_int2(r, __float_as_int(w));
}

// ---------- W1 transpose+cast ----------
__global__ __launch_bounds__(256) void k_w1t(const float* __restrict__ W1, unsigned short* __restrict__ w1t) {
  int t = blockIdx.x * 256 + threadIdx.x;
  if (t >= INC * HID) return;
  int k = t / HID, n = t % HID;
  w1t[n * INC + k] = f2bf(W1[t]);
}

// ---------- GEMM1: h1[NN][256] (bf16) = x @ W1 ----------
// 128x256 tile, BK=64, 8 waves. A (HBM stream) prefetched distance-2 (P/Q reg
// sets); B (L2-resident) distance-1, issued BEFORE A so its wait leaves A's
// in-flight set untouched.
__global__ __launch_bounds__(512) void k_gemm1(const float* __restrict__ x,
                                               const unsigned short* __restrict__ w1t,
                                               unsigned short* __restrict__ h1) {
  __shared__ char smem[49152];
  unsigned short* As = (unsigned short*)smem;
  unsigned short* Bs = (unsigned short*)(smem + 16384);
  const int tid = threadIdx.x;
  const int lane = tid & 63;
  const int wid = tid >> 6;
  const int wm = wid >> 2;
  const int wn = wid & 3;
  const long bm = blockIdx.x;

  const int ar0 = tid >> 3, as7 = tid & 7;
  const int ar1 = (tid + 512) >> 3;
  long arow0 = bm * 128 + ar0; if (arow0 > NN - 1) arow0 = NN - 1;
  long arow1 = bm * 128 + ar1; if (arow1 > NN - 1) arow1 = NN - 1;
  const float* gA0 = x + arow0 * INC + as7 * 8;
  const float* gA1 = x + arow1 * INC + as7 * 8;
  const int aoff0 = (ar0 << 7) | ((as7 ^ (ar0 & 7)) << 4);
  const int aoff1 = (ar1 << 7) | ((as7 ^ (ar1 & 7)) << 4);

  f32x4 acc[4][4];
#pragma unroll
  for (int m = 0; m < 4; m++)
#pragma unroll
    for (int n = 0; n < 4; n++) acc[m][n] = (f32x4){0.f, 0.f, 0.f, 0.f};

  float4 Pa, Pb, Pc, Pd, Qa, Qb, Qc, Qd;  // A dist-2 sets
  uint4 rb0, rb1, rb2, rb3;               // B dist-1 set

#define LOAD_ASET(Va, Vb, Vc, Vd, KT)             \
  do {                                            \
    Va = *(const float4*)(gA0 + (KT));            \
    Vb = *(const float4*)(gA0 + (KT) + 4);        \
    Vc = *(const float4*)(gA1 + (KT));            \
    Vd = *(const float4*)(gA1 + (KT) + 4);        \
  } while (0)
#define LOAD_B(KT)                                                                         \
  do {                                                                                     \
    rb0 = *(const uint4*)(w1t + (long)(tid >> 3) * INC + (KT) + (tid & 7) * 8);            \
    rb1 = *(const uint4*)(w1t + (long)((tid + 512) >> 3) * INC + (KT) + (tid & 7) * 8);    \
    rb2 = *(const uint4*)(w1t + (long)((tid + 1024) >> 3) * INC + (KT) + (tid & 7) * 8);   \
    rb3 = *(const uint4*)(w1t + (long)((tid + 1536) >> 3) * INC + (KT) + (tid & 7) * 8);   \
  } while (0)
#define WRITE_ASET(Va, Vb, Vc, Vd)                                                         \
  do {                                                                                     \
    union { unsigned short us[8]; uint4 v; } u;                                            \
    u.us[0] = f2bf(Va.x); u.us[1] = f2bf(Va.y); u.us[2] = f2bf(Va.z);                      \
    u.us[3] = f2bf(Va.w); u.us[4] = f2bf(Vb.x); u.us[5] = f2bf(Vb.y);                      \
    u.us[6] = f2bf(Vb.z); u.us[7] = f2bf(Vb.w);                                            \
    *(uint4*)((char*)As + aoff0) = u.v;                                                    \
    u.us[0] = f2bf(Vc.x); u.us[1] = f2bf(Vc.y); u.us[2] = f2bf(Vc.z);                      \
    u.us[3] = f2bf(Vc.w); u.us[4] = f2bf(Vd.x); u.us[5] = f2bf(Vd.y);                      \
    u.us[6] = f2bf(Vd.z); u.us[7] = f2bf(Vd.w);                                            \
    *(uint4*)((char*)As + aoff1) = u.v;                                                    \
  } while (0)
#define WRITE_B()                                                                          \
  do {                                                                                     \
    int r0 = tid >> 3, s7 = tid & 7;                                                       \
    *(uint4*)((char*)Bs + ((r0 << 7) | ((s7 ^ (r0 & 7)) << 4))) = rb0;                     \
    int r1 = (tid + 512) >> 3;                                                             \
    *(uint4*)((char*)Bs + ((r1 << 7) | ((s7 ^ (r1 & 7)) << 4))) = rb1;                     \
    int r2 = (tid + 1024) >> 3;                                                            \
    *(uint4*)((char*)Bs + ((r2 << 7) | ((s7 ^ (r2 & 7)) << 4))) = rb2;                     \
    int r3 = (tid + 1536) >> 3;                                                            \
    *(uint4*)((char*)Bs + ((r3 << 7) | ((s7 ^ (r3 & 7)) << 4))) = rb3;                     \
  } while (0)
#define MFMA_STEP()                                                                        \
  do {                                                                                     \
    _Pragma("unroll")                                                                      \
    for (int half = 0; half < 2; half++) {                                                 \
      bf16x8 af[4], bff[4];                                                                \
      int j = (half << 2) + (lane >> 4);                                                   \
      _Pragma("unroll")                                                                    \
      for (int m = 0; m < 4; m++) {                                                        \
        int row = wm * 64 + m * 16 + (lane & 15);                                          \
        af[m] = *(const bf16x8*)((const char*)As + ((row << 7) | ((j ^ (row & 7)) << 4))); \
      }                                                                                    \
      _Pragma("unroll")                                                                    \
      for (int n = 0; n < 4; n++) {                                                        \
        int row = wn * 64 + n * 16 + (lane & 15);                                          \
        bff[n] = *(const bf16x8*)((const char*)Bs + ((row << 7) | ((j ^ (row & 7)) << 4)));\
      }                                                                                    \
      _Pragma("unroll")                                                                    \
      for (int m = 0; m < 4; m++)                                                          \
        _Pragma("unroll")                                                                  \
        for (int n = 0; n < 4; n++)                                                        \
          acc[m][n] = __builtin_amdgcn_mfma_f32_16x16x32_bf16(af[m], bff[n], acc[m][n], 0, 0, 0); \
    }                                                                                      \
  } while (0)

  // prologue: A@0 -> P, B@0, A@64 -> Q  (2 A-tiles in flight)
  LOAD_ASET(Pa, Pb, Pc, Pd, 0);
  LOAD_B(0);
  LOAD_ASET(Qa, Qb, Qc, Qd, 64);

#pragma unroll 1
  for (int u = 0; u < 6; u++) {
    int kt = u * 128;
    // even tile kt (in P); Q (tile kt+64) stays in flight
    WRITE_ASET(Pa, Pb, Pc, Pd);
    WRITE_B();
    __syncthreads();
    if (kt + 64 < INC) LOAD_B(kt + 64);                       // B first
    if (kt + 128 < INC) LOAD_ASET(Pa, Pb, Pc, Pd, kt + 128);  // A dist-2
    MFMA_STEP();
    __syncthreads();
    // odd tile kt+64 (in Q)
    WRITE_ASET(Qa, Qb, Qc, Qd);
    WRITE_B();
    __syncthreads();
    if (kt + 128 < INC) LOAD_B(kt + 128);
    if (kt + 192 < INC) LOAD_ASET(Qa, Qb, Qc, Qd, kt + 192);
    MFMA_STEP();
    __syncthreads();
  }
#undef LOAD_ASET
#undef LOAD_B
#undef WRITE_ASET
#undef WRITE_B
#undef MFMA_STEP

  // epilogue: stage 64-row half-tiles in LDS, copy out full rows
  unsigned short* Os = (unsigned short*)smem;  // [64][264]
#pragma unroll
  for (int chunk = 0; chunk < 2; chunk++) {
    if (wm == chunk) {
#pragma unroll
      for (int m = 0; m < 4; m++)
#pragma unroll
        for (int n = 0; n < 4; n++) {
          int lrow = m * 16 + ((lane >> 4) << 2);
          int lcol = wn * 64 + n * 16 + (lane & 15);
#pragma unroll
          for (int r = 0; r < 4; r++)
            Os[(lrow + r) * 264 + lcol] = f2bf(acc[m][n][r]);
        }
    }
    __syncthreads();
    {
      int r = tid >> 3, s = tid & 7;
      long grow = bm * 128 + chunk * 64 + r;
      if (grow < NN) {
        unsigned short* dst = h1 + grow * HID;
#pragma unroll
        for (int i = 0; i < 4; i++) {
          int seg = s + i * 8;
          *(uint4*)(dst + seg * 8) = *(const uint4*)((const char*)Os + (long)r * 528 + seg * 16);
        }
      }
    }
    __syncthreads();
  }
}

// ---------- agg1 fused with relu+b1+W2 (R5 form: wave/node, ushort4, unroll x8) ----------
__global__ __launch_bounds__(256) void k_agg1(const unsigned short* __restrict__ h1,
                                              const float* __restrict__ dinv,
                                              const int* __restrict__ rowptr,
                                              const int2* __restrict__ epk,
                                              const float* __restrict__ b1,
                                              const float* __restrict__ W2,
                                              float* __restrict__ h2) {
  int w = (int)((blockIdx.x * 256 + threadIdx.x) >> 6);
  int lane = threadIdx.x & 63;
  if (w >= NN) return;
  float di = dinv[w];
  int c4 = lane << 2;
  const unsigned short* hb = h1 + c4;
  ushort4 hv = *(const ushort4*)(hb + (long)w * HID);
  float self = di * di;
  float a0 = self * bf2f(hv.x), a1 = self * bf2f(hv.y);
  float a2 = self * bf2f(hv.z), a3 = self * bf2f(hv.w);
  int e = rowptr[w], e1 = rowptr[w + 1];
  if ((e & 1) && e < e1) {
    int2 q = epk[e];
    float ws = __int_as_float(q.y);
    ushort4 g = *(const ushort4*)(hb + (long)q.x * HID);
    a0 += ws * bf2f(g.x); a1 += ws * bf2f(g.y);
    a2 += ws * bf2f(g.z); a3 += ws * bf2f(g.w);
    e++;
  }
  for (; e + 8 <= e1; e += 8) {
    uint4 p0 = *(const uint4*)(epk + e);
    uint4 p1 = *(const uint4*)(epk + e + 2);
    uint4 p2 = *(const uint4*)(epk + e + 4);
    uint4 p3 = *(const uint4*)(epk + e + 6);
    ushort4 g0 = *(const ushort4*)(hb + (long)(int)p0.x * HID);
    ushort4 g1 = *(const ushort4*)(hb + (long)(int)p0.z * HID);
    ushort4 g2 = *(const ushort4*)(hb + (long)(int)p1.x * HID);
    ushort4 g3 = *(const ushort4*)(hb + (long)(int)p1.z * HID);
    ushort4 g4 = *(const ushort4*)(hb + (long)(int)p2.x * HID);
    ushort4 g5 = *(const ushort4*)(hb + (long)(int)p2.z * HID);
    ushort4 g6 = *(const ushort4*)(hb + (long)(int)p3.x * HID);
    ushort4 g7 = *(const ushort4*)(hb + (long)(int)p3.z * HID);
    float w0 = __uint_as_float(p0.y), w1 = __uint_as_float(p0.w);
    float w2 = __uint_as_float(p1.y), w3 = __uint_as_float(p1.w);
    float w4 = __uint_as_float(p2.y), w5 = __uint_as_float(p2.w);
    float w6 = __uint_as_float(p3.y), w7 = __uint_as_float(p3.w);
    a0 += w0 * bf2f(g0.x) + w1 * bf2f(g1.x) + w2 * bf2f(g2.x) + w3 * bf2f(g3.x) +
          w4 * bf2f(g4.x) + w5 * bf2f(g5.x) + w6 * bf2f(g6.x) + w7 * bf2f(g7.x);
    a1 += w0 * bf2f(g0.y) + w1 * bf2f(g1.y) + w2 * bf2f(g2.y) + w3 * bf2f(g3.y) +
          w4 * bf2f(g4.y) + w5 * bf2f(g5.y) + w6 * bf2f(g6.y) + w7 * bf2f(g7.y);
    a2 += w0 * bf2f(g0.z) + w1 * bf2f(g1.z) + w2 * bf2f(g2.z) + w3 * bf2f(g3.z) +
          w4 * bf2f(g4.z) + w5 * bf2f(g5.z) + w6 * bf2f(g6.z) + w7 * bf2f(g7.z);
    a3 += w0 * bf2f(g0.w) + w1 * bf2f(g1.w) + w2 * bf2f(g2.w) + w3 * bf2f(g3.w) +
          w4 * bf2f(g4.w) + w5 * bf2f(g5.w) + w6 * bf2f(g6.w) + w7 * bf2f(g7.w);
  }
  for (; e + 2 <= e1; e += 2) {
    uint4 p = *(const uint4*)(epk + e);
    ushort4 g0 = *(const ushort4*)(hb + (long)(int)p.x * HID);
    ushort4 g1 = *(const ushort4*)(hb + (long)(int)p.z * HID);
    float w0 = __uint_as_float(p.y), w1 = __uint_as_float(p.w);
    a0 += w0 * bf2f(g0.x) + w1 * bf2f(g1.x);
    a1 += w0 * bf2f(g0.y) + w1 * bf2f(g1.y);
    a2 += w0 * bf2f(g0.z) + w1 * bf2f(g1.z);
    a3 += w0 * bf2f(g0.w) + w1 * bf2f(g1.w);
  }
  if (e < e1) {
    int2 q = epk[e];
    float ws = __int_as_float(q.y);
    ushort4 g = *(const ushort4*)(hb + (long)q.x * HID);
    a0 += ws * bf2f(g.x); a1 += ws * bf2f(g.y);
    a2 += ws * bf2f(g.z); a3 += ws * bf2f(g.w);
  }
  float4 bv = *(const float4*)(b1 + c4);
  float v0 = a0 + bv.x; v0 = v0 > 0.f ? v0 : 0.f;
  float v1 = a1 + bv.y; v1 = v1 > 0.f ? v1 : 0.f;
  float v2 = a2 + bv.z; v2 = v2 > 0.f ? v2 : 0.f;
  float v3 = a3 + bv.w; v3 = v3 > 0.f ? v3 : 0.f;
  const float4* wp = (const float4*)(W2 + ((long)c4 << 3));
  float4 r0a = wp[0], r0b = wp[1], r1a = wp[2], r1b = wp[3];
  float4 r2a = wp[4], r2b = wp[5], r3a = wp[6], r3b = wp[7];
  float p[8];
  p[0] = v0 * r0a.x + v1 * r1a.x + v2 * r2a.x + v3 * r3a.x;
  p[1] = v0 * r0a.y + v1 * r1a.y + v2 * r2a.y + v3 * r3a.y;
  p[2] = v0 * r0a.z + v1 * r1a.z + v2 * r2a.z + v3 * r3a.z;
  p[3] = v0 * r0a.w + v1 * r1a.w + v2 * r2a.w + v3 * r3a.w;
  p[4] = v0 * r0b.x + v1 * r1b.x + v2 * r2b.x + v3 * r3b.x;
  p[5] = v0 * r0b.y + v1 * r1b.y + v2 * r2b.y + v3 * r3b.y;
  p[6] = v0 * r0b.z + v1 * r1b.z + v2 * r2b.z + v3 * r3b.z;
  p[7] = v0 * r0b.w + v1 * r1b.w + v2 * r2b.w + v3 * r3b.w;
#pragma unroll
  for (int c = 0; c < 8; c++)
#pragma unroll
    for (int off = 1; off < 64; off <<= 1) p[c] += __shfl_xor(p[c], off, 64);
  if (lane < 8) {
    float o = p[0];
    o = (lane == 1) ? p[1] : o;
    o = (lane == 2) ? p[2] : o;
    o = (lane == 3) ? p[3] : o;
    o = (lane == 4) ? p[4] : o;
    o = (lane == 5) ? p[5] : o;
    o = (lane == 6) ? p[6] : o;
    o = (lane == 7) ? p[7] : o;
    h2[(long)w * NCLS + lane] = o;
  }
}

// ---------- agg2 + bias -> out (unroll x8) ----------
__global__ __launch_bounds__(256) void k_agg2(const float* __restrict__ h2,
                                              const float* __restrict__ dinv,
                                              const int* __restrict__ rowptr,
                                              const int2* __restrict__ epk,
                                              const float* __restrict__ b2,
                                              float* __restrict__ out) {
  long t = (long)blockIdx.x * 256 + threadIdx.x;
  long i = t >> 3;
  int c = (int)(t & 7);
  if (i >= NN) return;
  float di = dinv[i];
  float s = di * di * h2[i * NCLS + c];
  int e = rowptr[i], e1 = rowptr[i + 1];
  for (; e + 8 <= e1; e += 8) {
    int2 q0 = epk[e],     q1 = epk[e + 1], q2 = epk[e + 2], q3 = epk[e + 3];
    int2 q4 = epk[e + 4], q5 = epk[e + 5], q6 = epk[e + 6], q7 = epk[e + 7];
    float g0 = h2[(long)q0.x * NCLS + c], g1 = h2[(long)q1.x * NCLS + c];
    float g2 = h2[(long)q2.x * NCLS + c], g3 = h2[(long)q3.x * NCLS + c];
    float g4 = h2[(long)q4.x * NCLS + c], g5 = h2[(long)q5.x * NCLS + c];
    float g6 = h2[(long)q6.x * NCLS + c], g7 = h2[(long)q7.x * NCLS + c];
    s += __int_as_float(q0.y) * g0 + __int_as_float(q1.y) * g1 +
         __int_as_float(q2.y) * g2 + __int_as_float(q3.y) * g3 +
         __int_as_float(q4.y) * g4 + __int_as_float(q5.y) * g5 +
         __int_as_float(q6.y) * g6 + __int_as_float(q7.y) * g7;
  }
  for (; e < e1; e++) {
    int2 q = epk[e];
    s += __int_as_float(q.y) * h2[(long)q.x * NCLS + c];
  }
  out[i * NCLS + c] = s + b2[c];
}

extern "C" void kernel_launch(void* const* d_in, const int* in_sizes, int n_in,
                              void* d_out, int out_size, void* d_ws, size_t ws_size,
                              hipStream_t stream) {
  (void)in_sizes; (void)n_in; (void)out_size; (void)ws_size;
  const float* x  = (const float*)d_in[0];
  const int*   ei = (const int*)d_in[1];
  const float* W1 = (const float*)d_in[2];
  const float* b1 = (const float*)d_in[3];
  const float* W2 = (const float*)d_in[4];
  const float* b2 = (const float*)d_in[5];
  float* out = (float*)d_out;
  char* ws = (char*)d_ws;

  unsigned short* h1   = (unsigned short*)(ws + 0L);          // 51,200,000
  float* h2            = (float*)(ws + 51200000L);            // 3,200,000
  float* dinv          = (float*)(ws + 54400000L);            // 400,000
  int*   cnt           = (int*)(ws + 54800000L);              // 400,000
  int*   rowptr        = (int*)(ws + 55200000L);              // 400,004 (+pad)
  int*   cursor        = (int*)(ws + 55600128L);              // 400,000
  int2*  epk           = (int2*)(ws + 56000128L);             // 12,800,000
  unsigned short* w1t  = (unsigned short*)(ws + 68800128L);   // 393,216
  int*   bsum          = (int*)(ws + 69195008L);              // 1,564
  int*   boff          = (int*)(ws + 69196608L);              // 1,564

  hipMemsetAsync(cnt, 0, NN * sizeof(int), stream);
  k_count<<<(NE + 255) / 256, 256, 0, stream>>>(ei, cnt);
  k_scan1<<<NBLK, 256, 0, stream>>>(cnt, bsum, dinv);
  k_scan2<<<1, 512, 0, stream>>>(bsum, boff, rowptr);
  k_scan3<<<NBLK, 256, 0, stream>>>(cnt, boff, rowptr, cursor);
  k_fill<<<(NE + 255) / 256, 256, 0, stream>>>(ei, dinv, cursor, epk);
  k_w1t<<<(INC * HID + 255) / 256, 256, 0, stream>>>(W1, w1t);
  k_gemm1<<<782, 512, 0, stream>>>(x, w1t, h1);
  k_agg1<<<(NN * 64 + 255) / 256, 256, 0, stream>>>(h1, dinv, rowptr, epk, b1, W2, h2);
  k_agg2<<<(NN * NCLS + 255) / 256, 256, 0, stream>>>(h2, dinv, rowptr, epk, b2, out);
}